// Round 4
// baseline (751.915 us; speedup 1.0000x reference)
//
#include <hip/hip_runtime.h>
#include <hip/hip_bf16.h>
#include <math.h>

#define N_NODES 20000
#define N_EDGES 320000
#define N_GRAPHS 64

typedef __bf16 bf16_t;
typedef bf16_t bf16x8 __attribute__((ext_vector_type(8)));
typedef bf16_t bf16x4 __attribute__((ext_vector_type(4)));
typedef bf16_t bf16x2 __attribute__((ext_vector_type(2)));
typedef float f32x4 __attribute__((ext_vector_type(4)));
typedef float f32x2 __attribute__((ext_vector_type(2)));

// ---------------------------------------------------------------- CSR build
__global__ void hist_k(const int* __restrict__ dst, int* __restrict__ deg, int E) {
    int e = blockIdx.x * 256 + threadIdx.x;
    if (e < E) atomicAdd(&deg[dst[e]], 1);
}

// Wave-shuffle scan: 3 barriers per 1024-element chunk.
__global__ __launch_bounds__(1024) void scan_k(const int* __restrict__ deg,
                                               int* __restrict__ offs,
                                               int* __restrict__ cursor, int n) {
    __shared__ int s_ws[16];
    int tid = threadIdx.x;
    int lane = tid & 63, w = tid >> 6;
    int carry = 0;
    for (int base = 0; base < n; base += 1024) {
        int i = base + tid;
        int v = (i < n) ? deg[i] : 0;
        int x = v;
        #pragma unroll
        for (int off = 1; off < 64; off <<= 1) {
            int t = __shfl_up(x, off);
            if (lane >= off) x += t;
        }
        if (lane == 63) s_ws[w] = x;
        __syncthreads();
        if (tid < 16) {
            int y = s_ws[tid];
            #pragma unroll
            for (int off = 1; off < 16; off <<= 1) {
                int t = __shfl_up(y, off);
                if (tid >= off) y += t;
            }
            s_ws[tid] = y;
        }
        __syncthreads();
        int wbase = (w > 0) ? s_ws[w - 1] : 0;
        int ex = carry + wbase + x - v;
        if (i < n) { offs[i] = ex; cursor[i] = ex; }
        carry += s_ws[15];
        __syncthreads();  // protect s_ws before next chunk overwrites
    }
    if (tid == 0) offs[n] = carry;
}

__global__ void scatter_k(const int* __restrict__ src, const int* __restrict__ dst,
                          int* __restrict__ cursor, int* __restrict__ csr_src,
                          int* __restrict__ csr_eid, int E) {
    int e = blockIdx.x * 256 + threadIdx.x;
    if (e < E) {
        int d = dst[e];
        int p = atomicAdd(&cursor[d], 1);
        csr_src[p] = src[e];
        csr_eid[p] = e;
    }
}

// --------------------------------------------- weight transpose + bf16 cast
__global__ __launch_bounds__(256) void wt_k(const float* __restrict__ W,
                                            bf16_t* __restrict__ Bt, int K, int N) {
    __shared__ float t[32][33];
    int k0 = blockIdx.y * 32, n0 = blockIdx.x * 32;
    int tx = threadIdx.x & 31, ty = threadIdx.x >> 5;
    for (int i = ty; i < 32; i += 8) t[i][tx] = W[(size_t)(k0 + i) * N + n0 + tx];
    __syncthreads();
    for (int i = ty; i < 32; i += 8)
        Bt[(size_t)(n0 + i) * K + k0 + tx] = (bf16_t)t[tx][i];
}

// Permuted transpose for layer-3: Bt[n][k] = W[k][(n%6)*128 + n/6]
// -> GEMM output column n becomes h3i[j][n] with n = c*6 + h (interleaved).
__global__ void wtp3_k(const float* __restrict__ W, bf16_t* __restrict__ Bt) {
    int id = blockIdx.x * 256 + threadIdx.x;   // grid: 768 blocks of 256
    int n = id >> 8, k = id & 255;
    int pn = (n % 6) * 128 + n / 6;
    Bt[(size_t)n * 256 + k] = (bf16_t)W[(size_t)k * 768 + pn];
}

// ---------------------------------------------------------------- fp32 GEMM
// Used only for layer 1 (K=8).
template <typename OUT>
__global__ __launch_bounds__(256) void gemm_k(const float* __restrict__ A,
                                              const float* __restrict__ B,
                                              OUT* __restrict__ C,
                                              const float* __restrict__ bias,
                                              int M, int N, int K) {
    __shared__ float As[16][65];
    __shared__ float Bs[16][64];
    int tid = threadIdx.x;
    int tx = tid & 15, ty = tid >> 4;
    int row0 = blockIdx.y * 64, col0 = blockIdx.x * 64;
    float acc[4][4] = {};
    for (int k0 = 0; k0 < K; k0 += 16) {
        #pragma unroll
        for (int i = 0; i < 4; ++i) {
            int idx = tid + i * 256;
            int m = idx >> 4, kk = idx & 15;
            int gm = row0 + m, gk = k0 + kk;
            As[kk][m] = (gm < M && gk < K) ? A[(size_t)gm * K + gk] : 0.f;
        }
        #pragma unroll
        for (int i = 0; i < 4; ++i) {
            int idx = tid + i * 256;
            int kk = idx >> 6, n = idx & 63;
            int gk = k0 + kk, gn = col0 + n;
            Bs[kk][n] = (gk < K && gn < N) ? B[(size_t)gk * N + gn] : 0.f;
        }
        __syncthreads();
        #pragma unroll
        for (int kk = 0; kk < 16; ++kk) {
            float a[4], b[4];
            #pragma unroll
            for (int i = 0; i < 4; ++i) a[i] = As[kk][ty * 4 + i];
            #pragma unroll
            for (int j = 0; j < 4; ++j) b[j] = Bs[kk][tx * 4 + j];
            #pragma unroll
            for (int i = 0; i < 4; ++i)
                #pragma unroll
                for (int j = 0; j < 4; ++j) acc[i][j] += a[i] * b[j];
        }
        __syncthreads();
    }
    #pragma unroll
    for (int i = 0; i < 4; ++i) {
        int gm = row0 + ty * 4 + i;
        if (gm >= M) continue;
        #pragma unroll
        for (int j = 0; j < 4; ++j) {
            int gn = col0 + tx * 4 + j;
            if (gn < N) C[(size_t)gm * N + gn] = (OUT)(acc[i][j] + (bias ? bias[gn] : 0.f));
        }
    }
}

// ------------------------------------------------------------ bf16 MFMA GEMM
template <typename OUT>
__global__ __launch_bounds__(256) void gemm_bf16_k(
    const bf16_t* __restrict__ A, const bf16_t* __restrict__ Bt,
    OUT* __restrict__ C, const float* __restrict__ bias, int M, int N, int K) {
    __shared__ bf16_t As[128][40];
    __shared__ bf16_t Bs[128][40];
    int tid = threadIdx.x;
    int row0 = blockIdx.y * 128, col0 = blockIdx.x * 128;
    int wave = tid >> 6, lane = tid & 63, quad = lane >> 4, l16 = lane & 15;
    int wm = wave >> 1, wn = wave & 1;
    f32x4 acc[4][4] = {};
    int sr = tid >> 2;
    int sc = (tid & 3) * 8;
    for (int k0 = 0; k0 < K; k0 += 32) {
        #pragma unroll
        for (int half = 0; half < 2; ++half) {
            int r = sr + half * 64;
            int gm = row0 + r;
            bf16x8 v = {};
            if (gm < M) v = *(const bf16x8*)&A[(size_t)gm * K + k0 + sc];
            *(bf16x8*)&As[r][sc] = v;
            int gn = col0 + r;
            bf16x8 w = {};
            if (gn < N) w = *(const bf16x8*)&Bt[(size_t)gn * K + k0 + sc];
            *(bf16x8*)&Bs[r][sc] = w;
        }
        __syncthreads();
        bf16x8 af[4], bfr[4];
        #pragma unroll
        for (int i = 0; i < 4; ++i) {
            af[i] = *(const bf16x8*)&As[wm * 64 + i * 16 + l16][quad * 8];
            bfr[i] = *(const bf16x8*)&Bs[wn * 64 + i * 16 + l16][quad * 8];
        }
        #pragma unroll
        for (int i = 0; i < 4; ++i)
            #pragma unroll
            for (int j = 0; j < 4; ++j)
                acc[i][j] = __builtin_amdgcn_mfma_f32_16x16x32_bf16(af[i], bfr[j],
                                                                   acc[i][j], 0, 0, 0);
        __syncthreads();
    }
    #pragma unroll
    for (int i = 0; i < 4; ++i) {
        int base_m = row0 + wm * 64 + i * 16 + quad * 4;
        #pragma unroll
        for (int j = 0; j < 4; ++j) {
            int gn = col0 + wn * 64 + j * 16 + l16;
            float bv = bias ? bias[gn] : 0.f;
            #pragma unroll
            for (int r = 0; r < 4; ++r) {
                int gm = base_m + r;
                if (gm < M) C[(size_t)gm * N + gn] = (OUT)(acc[i][j][r] + bv);
            }
        }
    }
}

// ------------------------------------------------- attention scores as/ad
// Standard layout (layers 1-2).
__global__ void attn_k(const bf16_t* __restrict__ h, const float* __restrict__ a_s,
                       const float* __restrict__ a_d, float* __restrict__ as_,
                       float* __restrict__ ad_, int H, int C) {
    int j = blockIdx.x;
    int lane = threadIdx.x;  // 64
    const bf16_t* row = h + (size_t)j * H * C;
    int HC = H * C;
    float ss[6] = {}, dd[6] = {};
    for (int f = lane * 4; f < HC; f += 256) {
        bf16x4 v = *(const bf16x4*)&row[f];
        f32x4 a = *(const f32x4*)&a_s[f];
        f32x4 d = *(const f32x4*)&a_d[f];
        int hh = f / C;
        float s0 = 0.f, d0 = 0.f;
        #pragma unroll
        for (int i = 0; i < 4; ++i) {
            float x = (float)v[i];
            s0 += x * a[i];
            d0 += x * d[i];
        }
        ss[hh] += s0;
        dd[hh] += d0;
    }
    for (int hh = 0; hh < H; ++hh) {
        float s = ss[hh], d = dd[hh];
        #pragma unroll
        for (int off = 32; off; off >>= 1) {
            s += __shfl_xor(s, off);
            d += __shfl_xor(d, off);
        }
        if (lane == 0) { as_[j * H + hh] = s; ad_[j * H + hh] = d; }
    }
}

// Interleaved layout h3i[j][c*6+h] (layer 3, H=6, C=128). head = elem%6 == i.
__global__ void attn3i_k(const bf16_t* __restrict__ h3i, const float* __restrict__ a_s,
                         const float* __restrict__ a_d, float* __restrict__ as_,
                         float* __restrict__ ad_) {
    int j = blockIdx.x;
    int lane = threadIdx.x;  // 64
    const bf16_t* row = h3i + (size_t)j * 768;
    float ss[6] = {}, dd[6] = {};
    #pragma unroll
    for (int cc = 0; cc < 2; ++cc) {
        int c = lane + cc * 64;
        const bf16_t* p = row + c * 6;
        bf16x2 v0 = *(const bf16x2*)(p);
        bf16x2 v1 = *(const bf16x2*)(p + 2);
        bf16x2 v2 = *(const bf16x2*)(p + 4);
        float x[6] = {(float)v0[0], (float)v0[1], (float)v1[0],
                      (float)v1[1], (float)v2[0], (float)v2[1]};
        #pragma unroll
        for (int i = 0; i < 6; ++i) {
            ss[i] += x[i] * a_s[i * 128 + c];
            dd[i] += x[i] * a_d[i * 128 + c];
        }
    }
    #pragma unroll
    for (int i = 0; i < 6; ++i) {
        float s = ss[i], d = dd[i];
        #pragma unroll
        for (int off = 32; off; off >>= 1) {
            s += __shfl_xor(s, off);
            d += __shfl_xor(d, off);
        }
        if (lane == 0) { as_[j * 6 + i] = s; ad_[j * 6 + i] = d; }
    }
}

__device__ __forceinline__ float leaky02(float v) { return v > 0.f ? v : 0.2f * v; }

// ---------------------- aggregation, concat (H=4,C=64), XCD-sliced (8 x 32ch)
// slice = blockIdx & 7 -> all blocks of a slice land on one XCD (round-robin),
// so each XCD's L2 only holds 20000 x 64 B = 1.28 MB of h. Barrier-free:
// one wave per node (4 nodes per 256-thread block), shuffle reductions only.
__global__ __launch_bounds__(256) void agg_concat_s_k(
    const bf16_t* __restrict__ h, const float* __restrict__ as_,
    const float* __restrict__ ad_, const int* __restrict__ offs,
    const int* __restrict__ csr_src, const float* __restrict__ lin,
    const float* __restrict__ bgat, bf16_t* __restrict__ xb) {
    int b = blockIdx.x;
    int sl = b & 7;                 // slice -> XCD
    int j = (b >> 3) * 4 + (threadIdx.x >> 6);
    int t = threadIdx.x & 63;
    int head = sl >> 1;             // 32-ch slice lies in one 64-ch head
    int e_l = t >> 2, chunk = t & 3;
    int o0 = offs[j], deg = offs[j + 1] - o0;
    float adj = ad_[j * 4 + head];
    const char* hbase = (const char*)h + sl * 64 + chunk * 16;
    f32x4 a0 = {}, a1 = {};
    float wsum = 0.f;
    for (int e0 = 0; e0 < deg; e0 += 16) {
        int ne = deg - e0; if (ne > 16) ne = 16;
        if (e_l < ne) {
            int s = csr_src[o0 + e0 + e_l];
            float w = __expf(leaky02(as_[s * 4 + head] + adj));
            bf16x8 v = *(const bf16x8*)(hbase + (size_t)s * 512);
            wsum += w;
            #pragma unroll
            for (int i = 0; i < 4; ++i) a0[i] += w * (float)v[i];
            #pragma unroll
            for (int i = 0; i < 4; ++i) a1[i] += w * (float)v[4 + i];
        }
    }
    // full-wave reduce: each edge's w counted by its 4 chunk-lanes -> /4
    #pragma unroll
    for (int m = 1; m < 64; m <<= 1) wsum += __shfl_xor(wsum, m);
    float inv = 1.f / (wsum * 0.25f + 1e-16f);
    #pragma unroll
    for (int m = 4; m < 64; m <<= 1) {
        #pragma unroll
        for (int i = 0; i < 4; ++i) {
            a0[i] += __shfl_xor(a0[i], m);
            a1[i] += __shfl_xor(a1[i], m);
        }
    }
    if (t < 4) {                    // lane t holds chunk t totals (e_l==0)
        int cb = sl * 32 + t * 8;
        const float* lp = &lin[(size_t)j * 256 + cb];
        const float* bp = &bgat[cb];
        bf16x8 o;
        #pragma unroll
        for (int i = 0; i < 4; ++i)
            o[i] = (bf16_t)fmaxf(a0[i] * inv + bp[i] + lp[i], 0.f);
        #pragma unroll
        for (int i = 0; i < 4; ++i)
            o[4 + i] = (bf16_t)fmaxf(a1[i] * inv + bp[4 + i] + lp[4 + i], 0.f);
        *(bf16x8*)&xb[(size_t)j * 256 + cb] = o;
    }
}

// ------------- aggregation, mean (H=6,C=128), XCD-sliced on interleaved h3i
// h3i[j][c*6+h]; slice = blockIdx & 7 covers c in [sl*16, sl*16+16) -> 192 B
// contiguous per row, 3.84 MB slice footprint (fits one XCD L2). Each slice
// computes its 16 output channels completely (head-mean internal).
__global__ __launch_bounds__(192) void agg_mean_s_k(
    const bf16_t* __restrict__ h3i, const float* __restrict__ as_,
    const float* __restrict__ ad_, const int* __restrict__ offs,
    const int* __restrict__ csr_src, const int* __restrict__ csr_eid,
    const float* __restrict__ xres, const float* __restrict__ bgat,
    float* __restrict__ y, float* __restrict__ att) {
    int b = blockIdx.x;
    int sl = b & 7;
    int j = b >> 3;
    int tid = threadIdx.x;          // 192
    int o0 = offs[j], deg = offs[j + 1] - o0;
    __shared__ int s_src[16];
    __shared__ float s_w[16 * 6];
    __shared__ float s_wp[96];
    __shared__ float s_part[16][12][8];
    __shared__ float s_tot[96];
    __shared__ float s_inv[6];
    __shared__ float s_adj[6];
    if (tid < 6) s_adj[tid] = ad_[j * 6 + tid];
    int e_l = tid / 12, chunk = tid - e_l * 12;   // gather mapping
    int we = tid / 6, wh = tid - we * 6;          // weight mapping (tid<96)
    int q0 = chunk * 8;
    int hm[8];
    #pragma unroll
    for (int i = 0; i < 8; ++i) { int q = q0 + i; hm[i] = q % 6; }
    const char* hb2 = (const char*)h3i + sl * 192 + chunk * 16;
    f32x4 ac0 = {}, ac1 = {};
    float wrun = 0.f;
    __syncthreads();                // s_adj ready
    for (int e0 = 0; e0 < deg; e0 += 16) {
        int ne = deg - e0; if (ne > 16) ne = 16;
        if (tid < 96 && we < ne) {
            int s = csr_src[o0 + e0 + we];
            if (wh == 0) s_src[we] = s;
            float w = __expf(leaky02(as_[s * 6 + wh] + s_adj[wh]));
            s_w[we * 6 + wh] = w;
            wrun += w;
        }
        __syncthreads();
        if (e_l < ne) {
            int s = s_src[e_l];
            bf16x8 v = *(const bf16x8*)(hb2 + (size_t)s * 1536);
            #pragma unroll
            for (int i = 0; i < 4; ++i) ac0[i] += s_w[e_l * 6 + hm[i]] * (float)v[i];
            #pragma unroll
            for (int i = 0; i < 4; ++i) ac1[i] += s_w[e_l * 6 + hm[4 + i]] * (float)v[4 + i];
        }
        __syncthreads();
    }
    if (tid < 96) s_wp[tid] = wrun;
    *(f32x4*)&s_part[e_l][chunk][0] = ac0;
    *(f32x4*)&s_part[e_l][chunk][4] = ac1;
    __syncthreads();
    if (tid < 6) {
        float d = 0.f;
        #pragma unroll
        for (int e = 0; e < 16; ++e) d += s_wp[e * 6 + tid];
        s_inv[tid] = 1.f / (d + 1e-16f);
    }
    if (tid < 96) {
        int c2 = tid >> 3, i2 = tid & 7;
        float tt = 0.f;
        #pragma unroll
        for (int e = 0; e < 16; ++e) tt += s_part[e][c2][i2];
        s_tot[tid] = tt;
    }
    __syncthreads();
    if (tid < 16) {
        int abs_c = sl * 16 + tid;
        float sum = 0.f;
        #pragma unroll
        for (int hh = 0; hh < 6; ++hh) sum += s_tot[tid * 6 + hh] * s_inv[hh];
        y[(size_t)j * 128 + abs_c] =
            fmaxf(sum * (1.f / 6.f) + bgat[abs_c] + xres[(size_t)j * 128 + abs_c], 0.f);
    }
    if (sl == 0 && tid < 96) {
        // slice 0 writes normalized att (tables are L2-hot)
        float inv = s_inv[wh], adj = s_adj[wh];
        for (int e = we; e < deg; e += 16) {
            int p = o0 + e;
            int s = csr_src[p];
            att[(size_t)csr_eid[p] * 6 + wh] =
                __expf(leaky02(as_[s * 6 + wh] + adj)) * inv;
        }
    }
}

// ---------------------------------------------------------------- BatchNorm
__global__ void bn_stats_k(const float* __restrict__ y, float* __restrict__ sums, int N) {
    int c = threadIdx.x;  // 128
    float s = 0.f, q = 0.f;
    for (int r = blockIdx.x; r < N; r += gridDim.x) {
        float v = y[(size_t)r * 128 + c];
        s += v;
        q += v * v;
    }
    atomicAdd(&sums[c], s);
    atomicAdd(&sums[128 + c], q);
}
__global__ void bn_scale_k(const float* __restrict__ sums, const float* __restrict__ gamma,
                           const float* __restrict__ beta, float* __restrict__ scale,
                           float* __restrict__ shift, int N) {
    int c = threadIdx.x;
    float mu = sums[c] / (float)N;
    float var = fmaxf(sums[128 + c] / (float)N - mu * mu, 0.f);
    float inv = rsqrtf(var + 1e-5f) * gamma[c];
    scale[c] = inv;
    shift[c] = beta[c] - mu * inv;
}

// ---------------------------------------------------------------- max pool
__device__ __forceinline__ unsigned f2key(float f) {
    unsigned b = __float_as_uint(f);
    return (b & 0x80000000u) ? ~b : (b | 0x80000000u);
}
__global__ void pool_init_k(unsigned* __restrict__ pool_u) {
    int i = blockIdx.x * 256 + threadIdx.x;
    if (i < N_GRAPHS * 128) pool_u[i] = f2key(-3.402823466e38f * 2.0f);
}
__global__ void norm_pool_k(const float* __restrict__ y, const float* __restrict__ scale,
                            const float* __restrict__ shift, const int* __restrict__ batch,
                            unsigned* __restrict__ pool_u, int N) {
    int idx = blockIdx.x * 256 + threadIdx.x;
    if (idx >= N * 128) return;
    int n = idx >> 7, c = idx & 127;
    float v = y[idx] * scale[c] + shift[c];
    atomicMax(&pool_u[batch[n] * 128 + c], f2key(v));
}
__global__ void pool_write_k(const unsigned* __restrict__ pool_u, float* __restrict__ out) {
    int i = blockIdx.x * 256 + threadIdx.x;
    if (i < N_GRAPHS * 128) {
        unsigned u = pool_u[i];
        unsigned b = (u & 0x80000000u) ? (u & 0x7FFFFFFFu) : ~u;
        out[i] = __uint_as_float(b);
    }
}

// ================================================================ launcher
extern "C" void kernel_launch(void* const* d_in, const int* in_sizes, int n_in,
                              void* d_out, int out_size, void* d_ws, size_t ws_size,
                              hipStream_t stream) {
    const int N = N_NODES, E = N_EDGES;
    const float* x_ppi = (const float*)d_in[0];
    const int* edge = (const int*)d_in[1];
    const int* batch = (const int*)d_in[2];
    const float* W1 = (const float*)d_in[3];
    const float* a_src1 = (const float*)d_in[4];
    const float* a_dst1 = (const float*)d_in[5];
    const float* b_gat1 = (const float*)d_in[6];
    const float* lw1 = (const float*)d_in[7];
    const float* lb1 = (const float*)d_in[8];
    const float* W2 = (const float*)d_in[9];
    const float* a_src2 = (const float*)d_in[10];
    const float* a_dst2 = (const float*)d_in[11];
    const float* b_gat2 = (const float*)d_in[12];
    const float* lw2 = (const float*)d_in[13];
    const float* lb2 = (const float*)d_in[14];
    const float* W3 = (const float*)d_in[15];
    const float* a_src3 = (const float*)d_in[16];
    const float* a_dst3 = (const float*)d_in[17];
    const float* b_gat3 = (const float*)d_in[18];
    const float* lw3 = (const float*)d_in[19];
    const float* lb3 = (const float*)d_in[20];
    const float* bn_gamma = (const float*)d_in[21];
    const float* bn_beta = (const float*)d_in[22];

    const int* src = edge;
    const int* dst = edge + E;

    size_t off = 0;
    auto alloc = [&](size_t bytes) {
        size_t o = off;
        off = (off + bytes + 255) & ~(size_t)255;
        return o;
    };
    char* ws = (char*)d_ws;
    bf16_t* xb = (bf16_t*)(ws + alloc((size_t)N * 256 * 2));     // bf16 activations
    bf16_t* hb = (bf16_t*)(ws + alloc((size_t)N * 768 * 2));     // bf16 h (all layers)
    float* lin = (float*)(ws + alloc((size_t)N * 256 * 4));      // reused as y after L3
    float* x_res = (float*)(ws + alloc((size_t)N * 128 * 4));
    float* as_ = (float*)(ws + alloc((size_t)N * 6 * 4));
    float* ad_ = (float*)(ws + alloc((size_t)N * 6 * 4));
    int* deg = (int*)(ws + alloc((size_t)(N + 1) * 4));
    int* offs = (int*)(ws + alloc((size_t)(N + 1) * 4));
    int* cursor = (int*)(ws + alloc((size_t)(N + 1) * 4));
    int* csr_src = (int*)(ws + alloc((size_t)E * 4));
    int* csr_eid = (int*)(ws + alloc((size_t)E * 4));
    bf16_t* Wt2 = (bf16_t*)(ws + alloc((size_t)256 * 256 * 2));
    bf16_t* lwt2 = (bf16_t*)(ws + alloc((size_t)256 * 256 * 2));
    bf16_t* Wt3 = (bf16_t*)(ws + alloc((size_t)768 * 256 * 2));
    bf16_t* lwt3 = (bf16_t*)(ws + alloc((size_t)128 * 256 * 2));
    float* bn_sums = (float*)(ws + alloc(256 * 4));
    float* bn_scale = (float*)(ws + alloc(128 * 4));
    float* bn_shift = (float*)(ws + alloc(128 * 4));
    unsigned* pool_u = (unsigned*)(ws + alloc((size_t)N_GRAPHS * 128 * 4));

    float* out_pool = (float*)d_out;
    float* out_att = (float*)d_out + N_GRAPHS * 128;

    // ---- CSR + weight prep (independent)
    hipMemsetAsync(deg, 0, (size_t)N * 4, stream);
    hist_k<<<(E + 255) / 256, 256, 0, stream>>>(dst, deg, E);
    scan_k<<<1, 1024, 0, stream>>>(deg, offs, cursor, N);
    scatter_k<<<(E + 255) / 256, 256, 0, stream>>>(src, dst, cursor, csr_src, csr_eid, E);
    wt_k<<<dim3(8, 8), 256, 0, stream>>>(W2, Wt2, 256, 256);
    wt_k<<<dim3(8, 8), 256, 0, stream>>>(lw2, lwt2, 256, 256);
    wtp3_k<<<768, 256, 0, stream>>>(W3, Wt3);                    // permuted (interleaved out)
    wt_k<<<dim3(4, 8), 256, 0, stream>>>(lw3, lwt3, 256, 128);

    // ---- Layer 1 (in=8, fp32 GEMM — tiny K)
    gemm_k<bf16_t><<<dim3(4, 313), 256, 0, stream>>>(x_ppi, W1, hb, nullptr, N, 256, 8);
    gemm_k<float><<<dim3(4, 313), 256, 0, stream>>>(x_ppi, lw1, lin, lb1, N, 256, 8);
    attn_k<<<N, 64, 0, stream>>>(hb, a_src1, a_dst1, as_, ad_, 4, 64);
    agg_concat_s_k<<<N * 2, 256, 0, stream>>>(hb, as_, ad_, offs, csr_src, lin, b_gat1, xb);

    // ---- Layer 2 (256 -> 256, bf16 MFMA)
    gemm_bf16_k<bf16_t><<<dim3(2, 157), 256, 0, stream>>>(xb, Wt2, hb, nullptr, N, 256, 256);
    gemm_bf16_k<float><<<dim3(2, 157), 256, 0, stream>>>(xb, lwt2, lin, lb2, N, 256, 256);
    attn_k<<<N, 64, 0, stream>>>(hb, a_src2, a_dst2, as_, ad_, 4, 64);
    agg_concat_s_k<<<N * 2, 256, 0, stream>>>(hb, as_, ad_, offs, csr_src, lin, b_gat2, xb);

    // ---- Layer 3 (256 -> 6x128 mean + residual, bf16 MFMA, interleaved h3i)
    gemm_bf16_k<bf16_t><<<dim3(6, 157), 256, 0, stream>>>(xb, Wt3, hb, nullptr, N, 768, 256);
    gemm_bf16_k<float><<<dim3(1, 157), 256, 0, stream>>>(xb, lwt3, x_res, lb3, N, 128, 256);
    attn3i_k<<<N, 64, 0, stream>>>(hb, a_src3, a_dst3, as_, ad_);
    float* y = lin;  // reuse
    agg_mean_s_k<<<N * 8, 192, 0, stream>>>(hb, as_, ad_, offs, csr_src, csr_eid, x_res,
                                            b_gat3, y, out_att);

    // ---- BatchNorm (training stats, fused sum+sumsq pass)
    hipMemsetAsync(bn_sums, 0, 256 * 4, stream);
    bn_stats_k<<<160, 128, 0, stream>>>(y, bn_sums, N);
    bn_scale_k<<<1, 128, 0, stream>>>(bn_sums, bn_gamma, bn_beta, bn_scale, bn_shift, N);

    // ---- normalize + global max pool
    pool_init_k<<<(N_GRAPHS * 128 + 255) / 256, 256, 0, stream>>>(pool_u);
    norm_pool_k<<<((size_t)N * 128 + 255) / 256, 256, 0, stream>>>(y, bn_scale, bn_shift, batch,
                                                                   pool_u, N);
    pool_write_k<<<(N_GRAPHS * 128 + 255) / 256, 256, 0, stream>>>(pool_u, out_pool);
}

// Round 5
// 560.420 us; speedup vs baseline: 1.3417x; 1.3417x over previous
//
#include <hip/hip_runtime.h>
#include <hip/hip_bf16.h>
#include <math.h>

#define N_NODES 20000
#define N_EDGES 320000
#define N_GRAPHS 64

typedef __bf16 bf16_t;
typedef bf16_t bf16x8 __attribute__((ext_vector_type(8)));
typedef bf16_t bf16x4 __attribute__((ext_vector_type(4)));
typedef bf16_t bf16x2 __attribute__((ext_vector_type(2)));
typedef float f32x4 __attribute__((ext_vector_type(4)));
typedef float f32x2 __attribute__((ext_vector_type(2)));

// ---------------------------------------------------------------- CSR build
__global__ void hist_k(const int* __restrict__ dst, int* __restrict__ deg, int E) {
    int e = blockIdx.x * 256 + threadIdx.x;
    if (e < E) atomicAdd(&deg[dst[e]], 1);
}

// Wave-shuffle scan: 3 barriers per 1024-element chunk.
__global__ __launch_bounds__(1024) void scan_k(const int* __restrict__ deg,
                                               int* __restrict__ offs,
                                               int* __restrict__ cursor, int n) {
    __shared__ int s_ws[16];
    int tid = threadIdx.x;
    int lane = tid & 63, w = tid >> 6;
    int carry = 0;
    for (int base = 0; base < n; base += 1024) {
        int i = base + tid;
        int v = (i < n) ? deg[i] : 0;
        int x = v;
        #pragma unroll
        for (int off = 1; off < 64; off <<= 1) {
            int t = __shfl_up(x, off);
            if (lane >= off) x += t;
        }
        if (lane == 63) s_ws[w] = x;
        __syncthreads();
        if (tid < 16) {
            int y = s_ws[tid];
            #pragma unroll
            for (int off = 1; off < 16; off <<= 1) {
                int t = __shfl_up(y, off);
                if (tid >= off) y += t;
            }
            s_ws[tid] = y;
        }
        __syncthreads();
        int wbase = (w > 0) ? s_ws[w - 1] : 0;
        int ex = carry + wbase + x - v;
        if (i < n) { offs[i] = ex; cursor[i] = ex; }
        carry += s_ws[15];
        __syncthreads();  // protect s_ws before next chunk overwrites
    }
    if (tid == 0) offs[n] = carry;
}

__global__ void scatter_k(const int* __restrict__ src, const int* __restrict__ dst,
                          int* __restrict__ cursor, int* __restrict__ csr_src,
                          int* __restrict__ csr_eid, int E) {
    int e = blockIdx.x * 256 + threadIdx.x;
    if (e < E) {
        int d = dst[e];
        int p = atomicAdd(&cursor[d], 1);
        csr_src[p] = src[e];
        csr_eid[p] = e;
    }
}

// --------------------------------------------- weight transpose + bf16 cast
__global__ __launch_bounds__(256) void wt_k(const float* __restrict__ W,
                                            bf16_t* __restrict__ Bt, int K, int N) {
    __shared__ float t[32][33];
    int k0 = blockIdx.y * 32, n0 = blockIdx.x * 32;
    int tx = threadIdx.x & 31, ty = threadIdx.x >> 5;
    for (int i = ty; i < 32; i += 8) t[i][tx] = W[(size_t)(k0 + i) * N + n0 + tx];
    __syncthreads();
    for (int i = ty; i < 32; i += 8)
        Bt[(size_t)(n0 + i) * K + k0 + tx] = (bf16_t)t[tx][i];
}

// ---------------------------------------------------------------- fp32 GEMM
// Used only for layer 1 (K=8).
template <typename OUT>
__global__ __launch_bounds__(256) void gemm_k(const float* __restrict__ A,
                                              const float* __restrict__ B,
                                              OUT* __restrict__ C,
                                              const float* __restrict__ bias,
                                              int M, int N, int K) {
    __shared__ float As[16][65];
    __shared__ float Bs[16][64];
    int tid = threadIdx.x;
    int tx = tid & 15, ty = tid >> 4;
    int row0 = blockIdx.y * 64, col0 = blockIdx.x * 64;
    float acc[4][4] = {};
    for (int k0 = 0; k0 < K; k0 += 16) {
        #pragma unroll
        for (int i = 0; i < 4; ++i) {
            int idx = tid + i * 256;
            int m = idx >> 4, kk = idx & 15;
            int gm = row0 + m, gk = k0 + kk;
            As[kk][m] = (gm < M && gk < K) ? A[(size_t)gm * K + gk] : 0.f;
        }
        #pragma unroll
        for (int i = 0; i < 4; ++i) {
            int idx = tid + i * 256;
            int kk = idx >> 6, n = idx & 63;
            int gk = k0 + kk, gn = col0 + n;
            Bs[kk][n] = (gk < K && gn < N) ? B[(size_t)gk * N + gn] : 0.f;
        }
        __syncthreads();
        #pragma unroll
        for (int kk = 0; kk < 16; ++kk) {
            float a[4], b[4];
            #pragma unroll
            for (int i = 0; i < 4; ++i) a[i] = As[kk][ty * 4 + i];
            #pragma unroll
            for (int j = 0; j < 4; ++j) b[j] = Bs[kk][tx * 4 + j];
            #pragma unroll
            for (int i = 0; i < 4; ++i)
                #pragma unroll
                for (int j = 0; j < 4; ++j) acc[i][j] += a[i] * b[j];
        }
        __syncthreads();
    }
    #pragma unroll
    for (int i = 0; i < 4; ++i) {
        int gm = row0 + ty * 4 + i;
        if (gm >= M) continue;
        #pragma unroll
        for (int j = 0; j < 4; ++j) {
            int gn = col0 + tx * 4 + j;
            if (gn < N) C[(size_t)gm * N + gn] = (OUT)(acc[i][j] + (bias ? bias[gn] : 0.f));
        }
    }
}

// ------------------------------------------------------------ bf16 MFMA GEMM
template <typename OUT>
__global__ __launch_bounds__(256) void gemm_bf16_k(
    const bf16_t* __restrict__ A, const bf16_t* __restrict__ Bt,
    OUT* __restrict__ C, const float* __restrict__ bias, int M, int N, int K) {
    __shared__ bf16_t As[128][40];
    __shared__ bf16_t Bs[128][40];
    int tid = threadIdx.x;
    int row0 = blockIdx.y * 128, col0 = blockIdx.x * 128;
    int wave = tid >> 6, lane = tid & 63, quad = lane >> 4, l16 = lane & 15;
    int wm = wave >> 1, wn = wave & 1;
    f32x4 acc[4][4] = {};
    int sr = tid >> 2;
    int sc = (tid & 3) * 8;
    for (int k0 = 0; k0 < K; k0 += 32) {
        #pragma unroll
        for (int half = 0; half < 2; ++half) {
            int r = sr + half * 64;
            int gm = row0 + r;
            bf16x8 v = {};
            if (gm < M) v = *(const bf16x8*)&A[(size_t)gm * K + k0 + sc];
            *(bf16x8*)&As[r][sc] = v;
            int gn = col0 + r;
            bf16x8 w = {};
            if (gn < N) w = *(const bf16x8*)&Bt[(size_t)gn * K + k0 + sc];
            *(bf16x8*)&Bs[r][sc] = w;
        }
        __syncthreads();
        bf16x8 af[4], bfr[4];
        #pragma unroll
        for (int i = 0; i < 4; ++i) {
            af[i] = *(const bf16x8*)&As[wm * 64 + i * 16 + l16][quad * 8];
            bfr[i] = *(const bf16x8*)&Bs[wn * 64 + i * 16 + l16][quad * 8];
        }
        #pragma unroll
        for (int i = 0; i < 4; ++i)
            #pragma unroll
            for (int j = 0; j < 4; ++j)
                acc[i][j] = __builtin_amdgcn_mfma_f32_16x16x32_bf16(af[i], bfr[j],
                                                                   acc[i][j], 0, 0, 0);
        __syncthreads();
    }
    #pragma unroll
    for (int i = 0; i < 4; ++i) {
        int base_m = row0 + wm * 64 + i * 16 + quad * 4;
        #pragma unroll
        for (int j = 0; j < 4; ++j) {
            int gn = col0 + wn * 64 + j * 16 + l16;
            float bv = bias ? bias[gn] : 0.f;
            #pragma unroll
            for (int r = 0; r < 4; ++r) {
                int gm = base_m + r;
                if (gm < M) C[(size_t)gm * N + gn] = (OUT)(acc[i][j][r] + bv);
            }
        }
    }
}

// ------------------------------------------------- attention scores as/ad
__global__ void attn_k(const bf16_t* __restrict__ h, const float* __restrict__ a_s,
                       const float* __restrict__ a_d, float* __restrict__ as_,
                       float* __restrict__ ad_, int H, int C) {
    int j = blockIdx.x;
    int lane = threadIdx.x;  // 64
    const bf16_t* row = h + (size_t)j * H * C;
    int HC = H * C;
    float ss[6] = {}, dd[6] = {};
    for (int f = lane * 4; f < HC; f += 256) {
        bf16x4 v = *(const bf16x4*)&row[f];
        f32x4 a = *(const f32x4*)&a_s[f];
        f32x4 d = *(const f32x4*)&a_d[f];
        int hh = f / C;
        float s0 = 0.f, d0 = 0.f;
        #pragma unroll
        for (int i = 0; i < 4; ++i) {
            float x = (float)v[i];
            s0 += x * a[i];
            d0 += x * d[i];
        }
        ss[hh] += s0;
        dd[hh] += d0;
    }
    for (int hh = 0; hh < H; ++hh) {
        float s = ss[hh], d = dd[hh];
        #pragma unroll
        for (int off = 32; off; off >>= 1) {
            s += __shfl_xor(s, off);
            d += __shfl_xor(d, off);
        }
        if (lane == 0) { as_[j * H + hh] = s; ad_[j * H + hh] = d; }
    }
}

__device__ __forceinline__ float leaky02(float v) { return v > 0.f ? v : 0.2f * v; }

// ------------------------------------------- aggregation, concat (H=4,C=64)
// Single-pass no-max softmax + LDS w-precompute: per 64-edge chunk, 256
// threads compute each w[e][h]=exp(leaky(as+adj)) exactly once into LDS;
// gather threads then read w from LDS (no random global load, no exp).
__global__ __launch_bounds__(256) void agg_concat_k(
    const bf16_t* __restrict__ h, const float* __restrict__ as_,
    const float* __restrict__ ad_, const int* __restrict__ offs,
    const int* __restrict__ csr_src, const float* __restrict__ lin,
    const float* __restrict__ bgat, bf16_t* __restrict__ xb) {
    int j = blockIdx.x;
    int tid = threadIdx.x;  // 256
    int o0 = offs[j], deg = offs[j + 1] - o0;
    __shared__ float s_adj[4];
    __shared__ int s_src[64];
    __shared__ float s_w[64 * 4];
    __shared__ float s_ws4[4][4];
    __shared__ float s_inv[4];
    __shared__ float s_red[8][256];
    if (tid < 4) s_adj[tid] = ad_[j * 4 + tid];
    __syncthreads();
    int g = tid >> 5;               // edge group 0..7
    int u = tid & 31;               // 16-B chunk; channels u*8..u*8+7
    int myh = u >> 3;               // head
    const char* hbase = (const char*)h + u * 16;
    int ew = tid >> 2, hw = tid & 3;  // w-phase mapping: one (edge,head) each
    float adjw = s_adj[hw];
    f32x4 acc0 = {}, acc1 = {};
    float wrun = 0.f;
    for (int e0 = 0; e0 < deg; e0 += 64) {
        int ne = min(64, deg - e0);
        if (ew < ne) {
            int s = csr_src[o0 + e0 + ew];
            if (hw == 0) s_src[ew] = s;
            float w = __expf(leaky02(as_[s * 4 + hw] + adjw));
            s_w[ew * 4 + hw] = w;
            wrun += w;
        }
        __syncthreads();
        #pragma unroll 4
        for (int e = g; e < ne; e += 8) {
            int s = s_src[e];
            float w = s_w[e * 4 + myh];
            bf16x8 v = *(const bf16x8*)(hbase + (size_t)s * 512);
            #pragma unroll
            for (int i = 0; i < 4; ++i) acc0[i] += w * (float)v[i];
            #pragma unroll
            for (int i = 0; i < 4; ++i) acc1[i] += w * (float)v[4 + i];
        }
        __syncthreads();
    }
    // wrun: lanes sharing (lane&3)==hw; xor over 4..32 reduces within wave
    #pragma unroll
    for (int m = 4; m < 64; m <<= 1) wrun += __shfl_xor(wrun, m);
    int wave = tid >> 6, lane = tid & 63;
    if (lane < 4) s_ws4[wave][lane] = wrun;
    *(f32x4*)&s_red[g][u * 8] = acc0;
    *(f32x4*)&s_red[g][u * 8 + 4] = acc1;
    __syncthreads();
    if (tid < 4) {
        float d = s_ws4[0][tid] + s_ws4[1][tid] + s_ws4[2][tid] + s_ws4[3][tid];
        s_inv[tid] = 1.f / (d + 1e-16f);
    }
    __syncthreads();
    {
        int c = tid;
        float s = 0.f;
        #pragma unroll
        for (int g2 = 0; g2 < 8; ++g2) s += s_red[g2][c];
        float v = fmaxf(s * s_inv[c >> 6] + bgat[c] + lin[(size_t)j * 256 + c], 0.f);
        xb[(size_t)j * 256 + c] = (bf16_t)v;
    }
}

// --------------------------------------- aggregation, mean (H=6,C=128) + att
// Same structure: LDS w-precompute (384 w's by 192 threads, 2 each), then
// barrier-free-inner gather of the 1536-B rows; att swept by all threads.
__global__ __launch_bounds__(192) void agg_mean_k(
    const bf16_t* __restrict__ h, const float* __restrict__ as_,
    const float* __restrict__ ad_, const int* __restrict__ offs,
    const int* __restrict__ csr_src, const int* __restrict__ csr_eid,
    const float* __restrict__ xres, const float* __restrict__ bgat,
    float* __restrict__ y, float* __restrict__ att) {
    int j = blockIdx.x;
    int tid = threadIdx.x;  // 192
    int o0 = offs[j], deg = offs[j + 1] - o0;
    __shared__ float s_adj[6];
    __shared__ int s_src[64];
    __shared__ float s_w[64 * 6];
    __shared__ float s_wp[192];
    __shared__ float s_inv[6];
    __shared__ float s_red[2][768];
    if (tid < 6) s_adj[tid] = ad_[j * 6 + tid];
    __syncthreads();
    int g = tid / 96;               // edge group 0/1
    int u = tid - g * 96;           // 16-B chunk; channels u*8..u*8+7
    int myh = u >> 4;               // head
    const char* hbase = (const char*)h + u * 16;
    int hw = tid % 6;               // idx=tid and tid+192 share h (192%6==0)
    int ew0 = tid / 6;              // 0..31
    int ew1 = (tid + 192) / 6;      // 32..63
    float adjw = s_adj[hw];
    f32x4 acc0 = {}, acc1 = {};
    float wrun = 0.f;
    for (int e0 = 0; e0 < deg; e0 += 64) {
        int ne = min(64, deg - e0);
        if (ew0 < ne) {
            int s = csr_src[o0 + e0 + ew0];
            if (hw == 0) s_src[ew0] = s;
            float w = __expf(leaky02(as_[s * 6 + hw] + adjw));
            s_w[ew0 * 6 + hw] = w;
            wrun += w;
        }
        if (ew1 < ne) {
            int s = csr_src[o0 + e0 + ew1];
            if (hw == 0) s_src[ew1] = s;
            float w = __expf(leaky02(as_[s * 6 + hw] + adjw));
            s_w[ew1 * 6 + hw] = w;
            wrun += w;
        }
        __syncthreads();
        #pragma unroll 4
        for (int e = g; e < ne; e += 2) {
            int s = s_src[e];
            float w = s_w[e * 6 + myh];
            bf16x8 v = *(const bf16x8*)(hbase + (size_t)s * 1536);
            #pragma unroll
            for (int i = 0; i < 4; ++i) acc0[i] += w * (float)v[i];
            #pragma unroll
            for (int i = 0; i < 4; ++i) acc1[i] += w * (float)v[4 + i];
        }
        __syncthreads();
    }
    s_wp[tid] = wrun;
    *(f32x4*)&s_red[g][u * 8] = acc0;
    *(f32x4*)&s_red[g][u * 8 + 4] = acc1;
    __syncthreads();
    if (tid < 6) {
        float d = 0.f;
        #pragma unroll
        for (int k = 0; k < 32; ++k) d += s_wp[k * 6 + tid];
        s_inv[tid] = 1.f / (d + 1e-16f);
    }
    __syncthreads();
    if (tid < 128) {
        float s = 0.f;
        #pragma unroll
        for (int hh = 0; hh < 6; ++hh)
            s += (s_red[0][hh * 128 + tid] + s_red[1][hh * 128 + tid]) * s_inv[hh];
        y[(size_t)j * 128 + tid] =
            fmaxf(s * (1.f / 6.f) + bgat[tid] + xres[(size_t)j * 128 + tid], 0.f);
    }
    // att: all 192 threads sweep (edge, head) pairs; as_ is L2-hot
    for (int idx = tid; idx < deg * 6; idx += 192) {
        int e = idx / 6, hh = idx - e * 6;
        int p = o0 + e;
        int s = csr_src[p];
        att[(size_t)csr_eid[p] * 6 + hh] =
            __expf(leaky02(as_[s * 6 + hh] + s_adj[hh])) * s_inv[hh];
    }
}

// ---------------------------------------------------------------- BatchNorm
__global__ void bn_stats_k(const float* __restrict__ y, float* __restrict__ sums, int N) {
    int c = threadIdx.x;  // 128
    float s = 0.f, q = 0.f;
    for (int r = blockIdx.x; r < N; r += gridDim.x) {
        float v = y[(size_t)r * 128 + c];
        s += v;
        q += v * v;
    }
    atomicAdd(&sums[c], s);
    atomicAdd(&sums[128 + c], q);
}
__global__ void bn_scale_k(const float* __restrict__ sums, const float* __restrict__ gamma,
                           const float* __restrict__ beta, float* __restrict__ scale,
                           float* __restrict__ shift, int N) {
    int c = threadIdx.x;
    float mu = sums[c] / (float)N;
    float var = fmaxf(sums[128 + c] / (float)N - mu * mu, 0.f);
    float inv = rsqrtf(var + 1e-5f) * gamma[c];
    scale[c] = inv;
    shift[c] = beta[c] - mu * inv;
}

// ---------------------------------------------------------------- max pool
__device__ __forceinline__ unsigned f2key(float f) {
    unsigned b = __float_as_uint(f);
    return (b & 0x80000000u) ? ~b : (b | 0x80000000u);
}
__global__ void pool_init_k(unsigned* __restrict__ pool_u) {
    int i = blockIdx.x * 256 + threadIdx.x;
    if (i < N_GRAPHS * 128) pool_u[i] = f2key(-3.402823466e38f * 2.0f);
}
__global__ void norm_pool_k(const float* __restrict__ y, const float* __restrict__ scale,
                            const float* __restrict__ shift, const int* __restrict__ batch,
                            unsigned* __restrict__ pool_u, int N) {
    int idx = blockIdx.x * 256 + threadIdx.x;
    if (idx >= N * 128) return;
    int n = idx >> 7, c = idx & 127;
    float v = y[idx] * scale[c] + shift[c];
    atomicMax(&pool_u[batch[n] * 128 + c], f2key(v));
}
__global__ void pool_write_k(const unsigned* __restrict__ pool_u, float* __restrict__ out) {
    int i = blockIdx.x * 256 + threadIdx.x;
    if (i < N_GRAPHS * 128) {
        unsigned u = pool_u[i];
        unsigned b = (u & 0x80000000u) ? (u & 0x7FFFFFFFu) : ~u;
        out[i] = __uint_as_float(b);
    }
}

// ================================================================ launcher
extern "C" void kernel_launch(void* const* d_in, const int* in_sizes, int n_in,
                              void* d_out, int out_size, void* d_ws, size_t ws_size,
                              hipStream_t stream) {
    const int N = N_NODES, E = N_EDGES;
    const float* x_ppi = (const float*)d_in[0];
    const int* edge = (const int*)d_in[1];
    const int* batch = (const int*)d_in[2];
    const float* W1 = (const float*)d_in[3];
    const float* a_src1 = (const float*)d_in[4];
    const float* a_dst1 = (const float*)d_in[5];
    const float* b_gat1 = (const float*)d_in[6];
    const float* lw1 = (const float*)d_in[7];
    const float* lb1 = (const float*)d_in[8];
    const float* W2 = (const float*)d_in[9];
    const float* a_src2 = (const float*)d_in[10];
    const float* a_dst2 = (const float*)d_in[11];
    const float* b_gat2 = (const float*)d_in[12];
    const float* lw2 = (const float*)d_in[13];
    const float* lb2 = (const float*)d_in[14];
    const float* W3 = (const float*)d_in[15];
    const float* a_src3 = (const float*)d_in[16];
    const float* a_dst3 = (const float*)d_in[17];
    const float* b_gat3 = (const float*)d_in[18];
    const float* lw3 = (const float*)d_in[19];
    const float* lb3 = (const float*)d_in[20];
    const float* bn_gamma = (const float*)d_in[21];
    const float* bn_beta = (const float*)d_in[22];

    const int* src = edge;
    const int* dst = edge + E;

    size_t off = 0;
    auto alloc = [&](size_t bytes) {
        size_t o = off;
        off = (off + bytes + 255) & ~(size_t)255;
        return o;
    };
    char* ws = (char*)d_ws;
    bf16_t* xb = (bf16_t*)(ws + alloc((size_t)N * 256 * 2));     // bf16 activations
    bf16_t* hb = (bf16_t*)(ws + alloc((size_t)N * 768 * 2));     // bf16 h (all layers)
    float* lin = (float*)(ws + alloc((size_t)N * 256 * 4));      // reused as y after L3
    float* x_res = (float*)(ws + alloc((size_t)N * 128 * 4));
    float* as_ = (float*)(ws + alloc((size_t)N * 6 * 4));
    float* ad_ = (float*)(ws + alloc((size_t)N * 6 * 4));
    int* deg = (int*)(ws + alloc((size_t)(N + 1) * 4));
    int* offs = (int*)(ws + alloc((size_t)(N + 1) * 4));
    int* cursor = (int*)(ws + alloc((size_t)(N + 1) * 4));
    int* csr_src = (int*)(ws + alloc((size_t)E * 4));
    int* csr_eid = (int*)(ws + alloc((size_t)E * 4));
    bf16_t* Wt2 = (bf16_t*)(ws + alloc((size_t)256 * 256 * 2));
    bf16_t* lwt2 = (bf16_t*)(ws + alloc((size_t)256 * 256 * 2));
    bf16_t* Wt3 = (bf16_t*)(ws + alloc((size_t)768 * 256 * 2));
    bf16_t* lwt3 = (bf16_t*)(ws + alloc((size_t)128 * 256 * 2));
    float* bn_sums = (float*)(ws + alloc(256 * 4));
    float* bn_scale = (float*)(ws + alloc(128 * 4));
    float* bn_shift = (float*)(ws + alloc(128 * 4));
    unsigned* pool_u = (unsigned*)(ws + alloc((size_t)N_GRAPHS * 128 * 4));

    float* out_pool = (float*)d_out;
    float* out_att = (float*)d_out + N_GRAPHS * 128;

    // ---- CSR + weight prep (independent)
    hipMemsetAsync(deg, 0, (size_t)N * 4, stream);
    hist_k<<<(E + 255) / 256, 256, 0, stream>>>(dst, deg, E);
    scan_k<<<1, 1024, 0, stream>>>(deg, offs, cursor, N);
    scatter_k<<<(E + 255) / 256, 256, 0, stream>>>(src, dst, cursor, csr_src, csr_eid, E);
    wt_k<<<dim3(8, 8), 256, 0, stream>>>(W2, Wt2, 256, 256);
    wt_k<<<dim3(8, 8), 256, 0, stream>>>(lw2, lwt2, 256, 256);
    wt_k<<<dim3(24, 8), 256, 0, stream>>>(W3, Wt3, 256, 768);
    wt_k<<<dim3(4, 8), 256, 0, stream>>>(lw3, lwt3, 256, 128);

    // ---- Layer 1 (in=8, fp32 GEMM — tiny K)
    gemm_k<bf16_t><<<dim3(4, 313), 256, 0, stream>>>(x_ppi, W1, hb, nullptr, N, 256, 8);
    gemm_k<float><<<dim3(4, 313), 256, 0, stream>>>(x_ppi, lw1, lin, lb1, N, 256, 8);
    attn_k<<<N, 64, 0, stream>>>(hb, a_src1, a_dst1, as_, ad_, 4, 64);
    agg_concat_k<<<N, 256, 0, stream>>>(hb, as_, ad_, offs, csr_src, lin, b_gat1, xb);

    // ---- Layer 2 (256 -> 256, bf16 MFMA)
    gemm_bf16_k<bf16_t><<<dim3(2, 157), 256, 0, stream>>>(xb, Wt2, hb, nullptr, N, 256, 256);
    gemm_bf16_k<float><<<dim3(2, 157), 256, 0, stream>>>(xb, lwt2, lin, lb2, N, 256, 256);
    attn_k<<<N, 64, 0, stream>>>(hb, a_src2, a_dst2, as_, ad_, 4, 64);
    agg_concat_k<<<N, 256, 0, stream>>>(hb, as_, ad_, offs, csr_src, lin, b_gat2, xb);

    // ---- Layer 3 (256 -> 6x128 mean + residual, bf16 MFMA)
    gemm_bf16_k<bf16_t><<<dim3(6, 157), 256, 0, stream>>>(xb, Wt3, hb, nullptr, N, 768, 256);
    gemm_bf16_k<float><<<dim3(1, 157), 256, 0, stream>>>(xb, lwt3, x_res, lb3, N, 128, 256);
    attn_k<<<N, 64, 0, stream>>>(hb, a_src3, a_dst3, as_, ad_, 6, 128);
    float* y = lin;  // reuse
    agg_mean_k<<<N, 192, 0, stream>>>(hb, as_, ad_, offs, csr_src, csr_eid, x_res, b_gat3,
                                      y, out_att);

    // ---- BatchNorm (training stats, fused sum+sumsq pass)
    hipMemsetAsync(bn_sums, 0, 256 * 4, stream);
    bn_stats_k<<<160, 128, 0, stream>>>(y, bn_sums, N);
    bn_scale_k<<<1, 128, 0, stream>>>(bn_sums, bn_gamma, bn_beta, bn_scale, bn_shift, N);

    // ---- normalize + global max pool
    pool_init_k<<<(N_GRAPHS * 128 + 255) / 256, 256, 0, stream>>>(pool_u);
    norm_pool_k<<<((size_t)N * 128 + 255) / 256, 256, 0, stream>>>(y, bn_scale, bn_shift, batch,
                                                                   pool_u, N);
    pool_write_k<<<(N_GRAPHS * 128 + 255) / 256, 256, 0, stream>>>(pool_u, out_pool);
}

// Round 6
// 525.578 us; speedup vs baseline: 1.4306x; 1.0663x over previous
//
#include <hip/hip_runtime.h>
#include <hip/hip_bf16.h>
#include <math.h>

#define N_NODES 20000
#define N_EDGES 320000
#define N_GRAPHS 64

typedef __bf16 bf16_t;
typedef bf16_t bf16x8 __attribute__((ext_vector_type(8)));
typedef bf16_t bf16x4 __attribute__((ext_vector_type(4)));
typedef bf16_t bf16x2 __attribute__((ext_vector_type(2)));
typedef float f32x4 __attribute__((ext_vector_type(4)));
typedef float f32x2 __attribute__((ext_vector_type(2)));

// ---------------------------------------------------------------- CSR build
__global__ void hist_k(const int* __restrict__ dst, int* __restrict__ deg, int E) {
    int e = blockIdx.x * 256 + threadIdx.x;
    if (e < E) atomicAdd(&deg[dst[e]], 1);
}

// Wave-shuffle scan: 3 barriers per 1024-element chunk.
__global__ __launch_bounds__(1024) void scan_k(const int* __restrict__ deg,
                                               int* __restrict__ offs,
                                               int* __restrict__ cursor, int n) {
    __shared__ int s_ws[16];
    int tid = threadIdx.x;
    int lane = tid & 63, w = tid >> 6;
    int carry = 0;
    for (int base = 0; base < n; base += 1024) {
        int i = base + tid;
        int v = (i < n) ? deg[i] : 0;
        int x = v;
        #pragma unroll
        for (int off = 1; off < 64; off <<= 1) {
            int t = __shfl_up(x, off);
            if (lane >= off) x += t;
        }
        if (lane == 63) s_ws[w] = x;
        __syncthreads();
        if (tid < 16) {
            int y = s_ws[tid];
            #pragma unroll
            for (int off = 1; off < 16; off <<= 1) {
                int t = __shfl_up(y, off);
                if (tid >= off) y += t;
            }
            s_ws[tid] = y;
        }
        __syncthreads();
        int wbase = (w > 0) ? s_ws[w - 1] : 0;
        int ex = carry + wbase + x - v;
        if (i < n) { offs[i] = ex; cursor[i] = ex; }
        carry += s_ws[15];
        __syncthreads();  // protect s_ws before next chunk overwrites
    }
    if (tid == 0) offs[n] = carry;
}

__global__ void scatter_k(const int* __restrict__ src, const int* __restrict__ dst,
                          int* __restrict__ cursor, int* __restrict__ csr_src,
                          int* __restrict__ csr_eid, int E) {
    int e = blockIdx.x * 256 + threadIdx.x;
    if (e < E) {
        int d = dst[e];
        int p = atomicAdd(&cursor[d], 1);
        csr_src[p] = src[e];
        csr_eid[p] = e;
    }
}

// --------------------------------------------- weight transpose + bf16 cast
__global__ __launch_bounds__(256) void wt_k(const float* __restrict__ W,
                                            bf16_t* __restrict__ Bt, int K, int N) {
    __shared__ float t[32][33];
    int k0 = blockIdx.y * 32, n0 = blockIdx.x * 32;
    int tx = threadIdx.x & 31, ty = threadIdx.x >> 5;
    for (int i = ty; i < 32; i += 8) t[i][tx] = W[(size_t)(k0 + i) * N + n0 + tx];
    __syncthreads();
    for (int i = ty; i < 32; i += 8)
        Bt[(size_t)(n0 + i) * K + k0 + tx] = (bf16_t)t[tx][i];
}

// ---------------------------------------------------------------- fp32 GEMM
// Used only for layer 1 (K=8). Optional fused attention-score epilogue:
// as_o[gm*H + col0/Ch] = sum_c acc[gm][c] * asv[c]   (block covers one head)
template <typename OUT>
__global__ __launch_bounds__(256) void gemm_k(const float* __restrict__ A,
                                              const float* __restrict__ B,
                                              OUT* __restrict__ C,
                                              const float* __restrict__ bias,
                                              int M, int N, int K,
                                              const float* __restrict__ asv,
                                              const float* __restrict__ adv,
                                              float* __restrict__ as_o,
                                              float* __restrict__ ad_o,
                                              int H, int Ch) {
    __shared__ float As[16][65];
    __shared__ float Bs[16][64];
    int tid = threadIdx.x;
    int tx = tid & 15, ty = tid >> 4;
    int row0 = blockIdx.y * 64, col0 = blockIdx.x * 64;
    float acc[4][4] = {};
    for (int k0 = 0; k0 < K; k0 += 16) {
        #pragma unroll
        for (int i = 0; i < 4; ++i) {
            int idx = tid + i * 256;
            int m = idx >> 4, kk = idx & 15;
            int gm = row0 + m, gk = k0 + kk;
            As[kk][m] = (gm < M && gk < K) ? A[(size_t)gm * K + gk] : 0.f;
        }
        #pragma unroll
        for (int i = 0; i < 4; ++i) {
            int idx = tid + i * 256;
            int kk = idx >> 6, n = idx & 63;
            int gk = k0 + kk, gn = col0 + n;
            Bs[kk][n] = (gk < K && gn < N) ? B[(size_t)gk * N + gn] : 0.f;
        }
        __syncthreads();
        #pragma unroll
        for (int kk = 0; kk < 16; ++kk) {
            float a[4], b[4];
            #pragma unroll
            for (int i = 0; i < 4; ++i) a[i] = As[kk][ty * 4 + i];
            #pragma unroll
            for (int j = 0; j < 4; ++j) b[j] = Bs[kk][tx * 4 + j];
            #pragma unroll
            for (int i = 0; i < 4; ++i)
                #pragma unroll
                for (int j = 0; j < 4; ++j) acc[i][j] += a[i] * b[j];
        }
        __syncthreads();
    }
    #pragma unroll
    for (int i = 0; i < 4; ++i) {
        int gm = row0 + ty * 4 + i;
        if (gm >= M) continue;
        #pragma unroll
        for (int j = 0; j < 4; ++j) {
            int gn = col0 + tx * 4 + j;
            if (gn < N) C[(size_t)gm * N + gn] = (OUT)(acc[i][j] + (bias ? bias[gn] : 0.f));
        }
    }
    if (asv) {
        int hd = col0 / Ch;   // block's 64 cols lie in one head (Ch==64)
        float av[4], dv[4];
        #pragma unroll
        for (int j = 0; j < 4; ++j) {
            int ca = col0 + tx * 4 + j;
            av[j] = asv[ca];
            dv[j] = adv[ca];
        }
        #pragma unroll
        for (int i = 0; i < 4; ++i) {
            float sp = 0.f, sd = 0.f;
            #pragma unroll
            for (int j = 0; j < 4; ++j) { sp += acc[i][j] * av[j]; sd += acc[i][j] * dv[j]; }
            #pragma unroll
            for (int m = 1; m < 16; m <<= 1) {
                sp += __shfl_xor(sp, m);
                sd += __shfl_xor(sd, m);
            }
            if (tx == 0) {
                int gm = row0 + ty * 4 + i;
                if (gm < M) { as_o[gm * H + hd] = sp; ad_o[gm * H + hd] = sd; }
            }
        }
    }
}

// ------------------------------------------------------------ bf16 MFMA GEMM
// Optional fused attention-score epilogue. Ch==64: each wave's 64-col half is
// a complete head -> direct store. Ch==128: both wn halves contribute ->
// atomicAdd into pre-zeroed as_o/ad_o.
template <typename OUT>
__global__ __launch_bounds__(256) void gemm_bf16_k(
    const bf16_t* __restrict__ A, const bf16_t* __restrict__ Bt,
    OUT* __restrict__ C, const float* __restrict__ bias, int M, int N, int K,
    const float* __restrict__ asv, const float* __restrict__ adv,
    float* __restrict__ as_o, float* __restrict__ ad_o, int H, int Ch) {
    __shared__ bf16_t As[128][40];
    __shared__ bf16_t Bs[128][40];
    int tid = threadIdx.x;
    int row0 = blockIdx.y * 128, col0 = blockIdx.x * 128;
    int wave = tid >> 6, lane = tid & 63, quad = lane >> 4, l16 = lane & 15;
    int wm = wave >> 1, wn = wave & 1;
    f32x4 acc[4][4] = {};
    int sr = tid >> 2;
    int sc = (tid & 3) * 8;
    for (int k0 = 0; k0 < K; k0 += 32) {
        #pragma unroll
        for (int half = 0; half < 2; ++half) {
            int r = sr + half * 64;
            int gm = row0 + r;
            bf16x8 v = {};
            if (gm < M) v = *(const bf16x8*)&A[(size_t)gm * K + k0 + sc];
            *(bf16x8*)&As[r][sc] = v;
            int gn = col0 + r;
            bf16x8 w = {};
            if (gn < N) w = *(const bf16x8*)&Bt[(size_t)gn * K + k0 + sc];
            *(bf16x8*)&Bs[r][sc] = w;
        }
        __syncthreads();
        bf16x8 af[4], bfr[4];
        #pragma unroll
        for (int i = 0; i < 4; ++i) {
            af[i] = *(const bf16x8*)&As[wm * 64 + i * 16 + l16][quad * 8];
            bfr[i] = *(const bf16x8*)&Bs[wn * 64 + i * 16 + l16][quad * 8];
        }
        #pragma unroll
        for (int i = 0; i < 4; ++i)
            #pragma unroll
            for (int j = 0; j < 4; ++j)
                acc[i][j] = __builtin_amdgcn_mfma_f32_16x16x32_bf16(af[i], bfr[j],
                                                                   acc[i][j], 0, 0, 0);
        __syncthreads();
    }
    #pragma unroll
    for (int i = 0; i < 4; ++i) {
        int base_m = row0 + wm * 64 + i * 16 + quad * 4;
        #pragma unroll
        for (int j = 0; j < 4; ++j) {
            int gn = col0 + wn * 64 + j * 16 + l16;
            float bv = bias ? bias[gn] : 0.f;
            #pragma unroll
            for (int r = 0; r < 4; ++r) {
                int gm = base_m + r;
                if (gm < M) C[(size_t)gm * N + gn] = (OUT)(acc[i][j][r] + bv);
            }
        }
    }
    if (asv) {
        int hd = (col0 + wn * 64) / Ch;
        float av[4], dv[4];
        #pragma unroll
        for (int j = 0; j < 4; ++j) {
            int ca = col0 + wn * 64 + j * 16 + l16;
            av[j] = asv[ca];
            dv[j] = adv[ca];
        }
        #pragma unroll
        for (int i = 0; i < 4; ++i) {
            float sp[4] = {}, sd[4] = {};
            #pragma unroll
            for (int j = 0; j < 4; ++j)
                #pragma unroll
                for (int r = 0; r < 4; ++r) {
                    sp[r] += acc[i][j][r] * av[j];
                    sd[r] += acc[i][j][r] * dv[j];
                }
            #pragma unroll
            for (int m = 1; m < 16; m <<= 1)
                #pragma unroll
                for (int r = 0; r < 4; ++r) {
                    sp[r] += __shfl_xor(sp[r], m);
                    sd[r] += __shfl_xor(sd[r], m);
                }
            if (l16 == 0) {
                #pragma unroll
                for (int r = 0; r < 4; ++r) {
                    int gm = row0 + wm * 64 + i * 16 + quad * 4 + r;
                    if (gm < M) {
                        if (Ch == 128) {
                            atomicAdd(&as_o[gm * H + hd], sp[r]);
                            atomicAdd(&ad_o[gm * H + hd], sd[r]);
                        } else {
                            as_o[gm * H + hd] = sp[r];
                            ad_o[gm * H + hd] = sd[r];
                        }
                    }
                }
            }
        }
    }
}

__device__ __forceinline__ float leaky02(float v) { return v > 0.f ? v : 0.2f * v; }

// ------------------------------------------- aggregation, concat (H=4,C=64)
// Single-pass, no-max softmax: w = exp(leaky(as+ad)) computed per (thread,edge);
// normalize by 1/sum(w) at the end. Scores are O(5) max -> f32 exp is safe.
__global__ __launch_bounds__(256) void agg_concat_k(
    const bf16_t* __restrict__ h, const float* __restrict__ as_,
    const float* __restrict__ ad_, const int* __restrict__ offs,
    const int* __restrict__ csr_src, const float* __restrict__ lin,
    const float* __restrict__ bgat, bf16_t* __restrict__ xb) {
    int j = blockIdx.x;
    int tid = threadIdx.x;  // 256
    int o0 = offs[j], deg = offs[j + 1] - o0;
    __shared__ int s_src[64];
    __shared__ float s_adj[4];
    __shared__ float s_ws[8][4];
    __shared__ float s_inv[4];
    __shared__ float s_red[8][256];
    if (tid < 4) s_adj[tid] = ad_[j * 4 + tid];
    int g = tid >> 5;               // edge group 0..7
    int u = tid & 31;               // 16-B chunk; channels u*8..u*8+7
    int myh = u >> 3;               // head
    const char* hbase = (const char*)h + u * 16;
    f32x4 acc0 = {}, acc1 = {};
    float wsum = 0.f;
    for (int e0 = 0; e0 < deg; e0 += 64) {
        int ne = min(64, deg - e0);
        if (tid < ne) s_src[tid] = csr_src[o0 + e0 + tid];
        __syncthreads();
        float adj = s_adj[myh];
        #pragma unroll 2
        for (int e = g; e < ne; e += 8) {
            int s = s_src[e];
            float w = __expf(leaky02(as_[s * 4 + myh] + adj));
            bf16x8 v = *(const bf16x8*)(hbase + s * 512);
            wsum += w;
            #pragma unroll
            for (int i = 0; i < 4; ++i) acc0[i] += w * (float)v[i];
            #pragma unroll
            for (int i = 0; i < 4; ++i) acc1[i] += w * (float)v[4 + i];
        }
        __syncthreads();
    }
    if ((u & 7) == 0) s_ws[g][myh] = wsum;   // all 8 u's of (g,h) hold same wsum
    *(f32x4*)&s_red[g][u * 8] = acc0;
    *(f32x4*)&s_red[g][u * 8 + 4] = acc1;
    __syncthreads();
    if (tid < 4) {
        float d = 0.f;
        #pragma unroll
        for (int g2 = 0; g2 < 8; ++g2) d += s_ws[g2][tid];
        s_inv[tid] = 1.f / (d + 1e-16f);
    }
    __syncthreads();
    {
        int c = tid;
        float s = 0.f;
        #pragma unroll
        for (int g2 = 0; g2 < 8; ++g2) s += s_red[g2][c];
        float v = fmaxf(s * s_inv[c >> 6] + bgat[c] + lin[(size_t)j * 256 + c], 0.f);
        xb[(size_t)j * 256 + c] = (bf16_t)v;
    }
}

// --------------------------------------- aggregation, mean (H=6,C=128) + att
// Same single-pass no-max structure; wave 3 writes normalized att at the end.
__global__ __launch_bounds__(256) void agg_mean_k(
    const bf16_t* __restrict__ h, const float* __restrict__ as_,
    const float* __restrict__ ad_, const int* __restrict__ offs,
    const int* __restrict__ csr_src, const int* __restrict__ csr_eid,
    const float* __restrict__ xres, const float* __restrict__ bgat,
    float* __restrict__ y, float* __restrict__ att) {
    int j = blockIdx.x;
    int tid = threadIdx.x;  // 256
    int o0 = offs[j], deg = offs[j + 1] - o0;
    __shared__ int s_src[64];
    __shared__ float s_adj[6];
    __shared__ float s_ws[2][6];
    __shared__ float s_inv[6];
    __shared__ float s_red[2][768];
    if (tid < 6) s_adj[tid] = ad_[j * 6 + tid];
    int g = tid / 96;               // edge group 0/1 (tid<192)
    int u = tid - g * 96;           // 16-B chunk; channels u*8..u*8+7
    int myh = u >> 4;               // head
    const char* hbase = (const char*)h + u * 16;
    f32x4 acc0 = {}, acc1 = {};
    float wsum = 0.f;
    for (int e0 = 0; e0 < deg; e0 += 64) {
        int ne = min(64, deg - e0);
        if (tid < ne) s_src[tid] = csr_src[o0 + e0 + tid];
        __syncthreads();
        if (tid < 192) {
            float adj = s_adj[myh];
            #pragma unroll 4
            for (int e = g; e < ne; e += 2) {
                int s = s_src[e];
                float w = __expf(leaky02(as_[s * 6 + myh] + adj));
                bf16x8 v = *(const bf16x8*)(hbase + s * 1536);
                wsum += w;
                #pragma unroll
                for (int i = 0; i < 4; ++i) acc0[i] += w * (float)v[i];
                #pragma unroll
                for (int i = 0; i < 4; ++i) acc1[i] += w * (float)v[4 + i];
            }
        }
        __syncthreads();
    }
    if (tid < 192) {
        if ((u & 15) == 0) s_ws[g][myh] = wsum;  // 16 u's of (g,h) identical
        *(f32x4*)&s_red[g][u * 8] = acc0;
        *(f32x4*)&s_red[g][u * 8 + 4] = acc1;
    }
    __syncthreads();
    if (tid < 6) {
        float d = s_ws[0][tid] + s_ws[1][tid];
        s_inv[tid] = 1.f / (d + 1e-16f);
    }
    __syncthreads();
    if (tid < 128) {
        float s = 0.f;
        #pragma unroll
        for (int hh = 0; hh < 6; ++hh)
            s += (s_red[0][hh * 128 + tid] + s_red[1][hh * 128 + tid]) * s_inv[hh];
        y[(size_t)j * 128 + tid] =
            fmaxf(s * (1.f / 6.f) + bgat[tid] + xres[(size_t)j * 128 + tid], 0.f);
    } else if (tid >= 192) {
        // wave 3: recompute normalized alpha and write att (L2-resident tables)
        int t = tid - 192;
        for (int e = t; e < deg; e += 64) {
            int p = o0 + e;
            int s = csr_src[p];
            size_t eid = (size_t)csr_eid[p];
            #pragma unroll
            for (int hh = 0; hh < 6; ++hh) {
                float w = __expf(leaky02(as_[s * 6 + hh] + s_adj[hh])) * s_inv[hh];
                att[eid * 6 + hh] = w;
            }
        }
    }
}

// ---------------------------------------------------------------- BatchNorm
__global__ void bn_stats_k(const float* __restrict__ y, float* __restrict__ sums, int N) {
    int c = threadIdx.x;  // 128
    float s = 0.f, q = 0.f;
    for (int r = blockIdx.x; r < N; r += gridDim.x) {
        float v = y[(size_t)r * 128 + c];
        s += v;
        q += v * v;
    }
    atomicAdd(&sums[c], s);
    atomicAdd(&sums[128 + c], q);
}
__global__ void bn_scale_k(const float* __restrict__ sums, const float* __restrict__ gamma,
                           const float* __restrict__ beta, float* __restrict__ scale,
                           float* __restrict__ shift, int N) {
    int c = threadIdx.x;
    float mu = sums[c] / (float)N;
    float var = fmaxf(sums[128 + c] / (float)N - mu * mu, 0.f);
    float inv = rsqrtf(var + 1e-5f) * gamma[c];
    scale[c] = inv;
    shift[c] = beta[c] - mu * inv;
}

// ---------------------------------------------------------------- max pool
__device__ __forceinline__ unsigned f2key(float f) {
    unsigned b = __float_as_uint(f);
    return (b & 0x80000000u) ? ~b : (b | 0x80000000u);
}
__global__ void pool_init_k(unsigned* __restrict__ pool_u) {
    int i = blockIdx.x * 256 + threadIdx.x;
    if (i < N_GRAPHS * 128) pool_u[i] = f2key(-3.402823466e38f * 2.0f);
}
__global__ void norm_pool_k(const float* __restrict__ y, const float* __restrict__ scale,
                            const float* __restrict__ shift, const int* __restrict__ batch,
                            unsigned* __restrict__ pool_u, int N) {
    int idx = blockIdx.x * 256 + threadIdx.x;
    if (idx >= N * 128) return;
    int n = idx >> 7, c = idx & 127;
    float v = y[idx] * scale[c] + shift[c];
    atomicMax(&pool_u[batch[n] * 128 + c], f2key(v));
}
__global__ void pool_write_k(const unsigned* __restrict__ pool_u, float* __restrict__ out) {
    int i = blockIdx.x * 256 + threadIdx.x;
    if (i < N_GRAPHS * 128) {
        unsigned u = pool_u[i];
        unsigned b = (u & 0x80000000u) ? (u & 0x7FFFFFFFu) : ~u;
        out[i] = __uint_as_float(b);
    }
}

// ================================================================ launcher
extern "C" void kernel_launch(void* const* d_in, const int* in_sizes, int n_in,
                              void* d_out, int out_size, void* d_ws, size_t ws_size,
                              hipStream_t stream) {
    const int N = N_NODES, E = N_EDGES;
    const float* x_ppi = (const float*)d_in[0];
    const int* edge = (const int*)d_in[1];
    const int* batch = (const int*)d_in[2];
    const float* W1 = (const float*)d_in[3];
    const float* a_src1 = (const float*)d_in[4];
    const float* a_dst1 = (const float*)d_in[5];
    const float* b_gat1 = (const float*)d_in[6];
    const float* lw1 = (const float*)d_in[7];
    const float* lb1 = (const float*)d_in[8];
    const float* W2 = (const float*)d_in[9];
    const float* a_src2 = (const float*)d_in[10];
    const float* a_dst2 = (const float*)d_in[11];
    const float* b_gat2 = (const float*)d_in[12];
    const float* lw2 = (const float*)d_in[13];
    const float* lb2 = (const float*)d_in[14];
    const float* W3 = (const float*)d_in[15];
    const float* a_src3 = (const float*)d_in[16];
    const float* a_dst3 = (const float*)d_in[17];
    const float* b_gat3 = (const float*)d_in[18];
    const float* lw3 = (const float*)d_in[19];
    const float* lb3 = (const float*)d_in[20];
    const float* bn_gamma = (const float*)d_in[21];
    const float* bn_beta = (const float*)d_in[22];

    const int* src = edge;
    const int* dst = edge + E;

    size_t off = 0;
    auto alloc = [&](size_t bytes) {
        size_t o = off;
        off = (off + bytes + 255) & ~(size_t)255;
        return o;
    };
    char* ws = (char*)d_ws;
    bf16_t* xb = (bf16_t*)(ws + alloc((size_t)N * 256 * 2));     // bf16 activations
    bf16_t* hb = (bf16_t*)(ws + alloc((size_t)N * 768 * 2));     // bf16 h (all layers)
    float* lin = (float*)(ws + alloc((size_t)N * 256 * 4));      // reused as y after L3
    float* x_res = (float*)(ws + alloc((size_t)N * 128 * 4));
    float* as_ = (float*)(ws + alloc((size_t)N * 6 * 4));
    float* ad_ = (float*)(ws + alloc((size_t)N * 6 * 4));
    int* deg = (int*)(ws + alloc((size_t)(N + 1) * 4));
    int* offs = (int*)(ws + alloc((size_t)(N + 1) * 4));
    int* cursor = (int*)(ws + alloc((size_t)(N + 1) * 4));
    int* csr_src = (int*)(ws + alloc((size_t)E * 4));
    int* csr_eid = (int*)(ws + alloc((size_t)E * 4));
    bf16_t* Wt2 = (bf16_t*)(ws + alloc((size_t)256 * 256 * 2));
    bf16_t* lwt2 = (bf16_t*)(ws + alloc((size_t)256 * 256 * 2));
    bf16_t* Wt3 = (bf16_t*)(ws + alloc((size_t)768 * 256 * 2));
    bf16_t* lwt3 = (bf16_t*)(ws + alloc((size_t)128 * 256 * 2));
    float* bn_sums = (float*)(ws + alloc(256 * 4));
    float* bn_scale = (float*)(ws + alloc(128 * 4));
    float* bn_shift = (float*)(ws + alloc(128 * 4));
    unsigned* pool_u = (unsigned*)(ws + alloc((size_t)N_GRAPHS * 128 * 4));

    float* out_pool = (float*)d_out;
    float* out_att = (float*)d_out + N_GRAPHS * 128;

    // ---- CSR + weight prep (independent)
    hipMemsetAsync(deg, 0, (size_t)N * 4, stream);
    hist_k<<<(E + 255) / 256, 256, 0, stream>>>(dst, deg, E);
    scan_k<<<1, 1024, 0, stream>>>(deg, offs, cursor, N);
    scatter_k<<<(E + 255) / 256, 256, 0, stream>>>(src, dst, cursor, csr_src, csr_eid, E);
    wt_k<<<dim3(8, 8), 256, 0, stream>>>(W2, Wt2, 256, 256);
    wt_k<<<dim3(8, 8), 256, 0, stream>>>(lw2, lwt2, 256, 256);
    wt_k<<<dim3(24, 8), 256, 0, stream>>>(W3, Wt3, 256, 768);
    wt_k<<<dim3(4, 8), 256, 0, stream>>>(lw3, lwt3, 256, 128);

    // ---- Layer 1 (in=8, fp32 GEMM — tiny K); as/ad fused into h-GEMM epilogue
    gemm_k<bf16_t><<<dim3(4, 313), 256, 0, stream>>>(x_ppi, W1, hb, nullptr, N, 256, 8,
                                                     a_src1, a_dst1, as_, ad_, 4, 64);
    gemm_k<float><<<dim3(4, 313), 256, 0, stream>>>(x_ppi, lw1, lin, lb1, N, 256, 8,
                                                    nullptr, nullptr, nullptr, nullptr, 0, 1);
    agg_concat_k<<<N, 256, 0, stream>>>(hb, as_, ad_, offs, csr_src, lin, b_gat1, xb);

    // ---- Layer 2 (256 -> 256, bf16 MFMA); as/ad fused (each wave = full head)
    gemm_bf16_k<bf16_t><<<dim3(2, 157), 256, 0, stream>>>(xb, Wt2, hb, nullptr, N, 256, 256,
                                                          a_src2, a_dst2, as_, ad_, 4, 64);
    gemm_bf16_k<float><<<dim3(2, 157), 256, 0, stream>>>(xb, lwt2, lin, lb2, N, 256, 256,
                                                         nullptr, nullptr, nullptr, nullptr,
                                                         0, 1);
    agg_concat_k<<<N, 256, 0, stream>>>(hb, as_, ad_, offs, csr_src, lin, b_gat2, xb);

    // ---- Layer 3 (256 -> 6x128 mean + residual); C=128 head spans 2 waves ->
    // epilogue uses atomicAdd into pre-zeroed as_/ad_
    hipMemsetAsync(as_, 0, (size_t)N * 6 * 4, stream);
    hipMemsetAsync(ad_, 0, (size_t)N * 6 * 4, stream);
    gemm_bf16_k<bf16_t><<<dim3(6, 157), 256, 0, stream>>>(xb, Wt3, hb, nullptr, N, 768, 256,
                                                          a_src3, a_dst3, as_, ad_, 6, 128);
    gemm_bf16_k<float><<<dim3(1, 157), 256, 0, stream>>>(xb, lwt3, x_res, lb3, N, 128, 256,
                                                         nullptr, nullptr, nullptr, nullptr,
                                                         0, 1);
    float* y = lin;  // reuse
    agg_mean_k<<<N, 256, 0, stream>>>(hb, as_, ad_, offs, csr_src, csr_eid, x_res, b_gat3,
                                      y, out_att);

    // ---- BatchNorm (training stats, fused sum+sumsq pass)
    hipMemsetAsync(bn_sums, 0, 256 * 4, stream);
    bn_stats_k<<<160, 128, 0, stream>>>(y, bn_sums, N);
    bn_scale_k<<<1, 128, 0, stream>>>(bn_sums, bn_gamma, bn_beta, bn_scale, bn_shift, N);

    // ---- normalize + global max pool
    pool_init_k<<<(N_GRAPHS * 128 + 255) / 256, 256, 0, stream>>>(pool_u);
    norm_pool_k<<<((size_t)N * 128 + 255) / 256, 256, 0, stream>>>(y, bn_scale, bn_shift, batch,
                                                                   pool_u, N);
    pool_write_k<<<(N_GRAPHS * 128 + 255) / 256, 256, 0, stream>>>(pool_u, out_pool);
}